// Round 1
// baseline (1950.951 us; speedup 1.0000x reference)
//
#include <hip/hip_runtime.h>
#include <hip/hip_bf16.h>
#include <math.h>

#define T_STEPS 16
#define NN 4096
#define RR 256
#define CC 32

__device__ __forceinline__ float sigmoidf_(float x) { return 1.f / (1.f + __expf(-x)); }
__device__ __forceinline__ float tanh_fast(float x) { return 2.f / (1.f + __expf(-2.f * x)) - 1.f; }

// ---------------------------------------------------------------------------
// Pack W matrices into k-major transposed layout for coalesced GRU loads:
//   out[m][kq*1024 + i*4 + ks] = W_m[i][kq*4+ks]   (m = 0..3)
//   m=0: Wz+Uz, m=1: Wr+Ur, m=2: Wh, m=3: Uh
// Thread i in the GRU then loads float4 at (kq*1024 + i*4): consecutive lanes
// -> consecutive 16B -> perfectly coalesced.
// ---------------------------------------------------------------------------
__global__ __launch_bounds__(256) void pack_w(
    const float* __restrict__ Wz, const float* __restrict__ Uz,
    const float* __restrict__ Wr, const float* __restrict__ Ur,
    const float* __restrict__ Wh, const float* __restrict__ Uh,
    float* __restrict__ out)
{
    const int m   = blockIdx.y;
    const int idx = blockIdx.x * 256 + threadIdx.x;   // 0..65535
    const int kq  = idx >> 10;
    const int rem = idx & 1023;
    const int i   = rem >> 2;
    const int ks  = rem & 3;
    const int k   = kq * 4 + ks;
    const int src = i * RR + k;
    float v;
    if      (m == 0) v = Wz[src] + Uz[src];
    else if (m == 1) v = Wr[src] + Ur[src];
    else if (m == 2) v = Wh[src];
    else             v = Uh[src];
    out[m * 65536 + idx] = v;
}

// ---------------------------------------------------------------------------
// GRU recurrence. Column-separable: block j evolves column j of Q for all 16
// steps with only intra-block barriers. Thread i = row i.
//   z = sigmoid((Wz+Uz)@Q); r = sigmoid((Wr+Ur)@Q)
//   h = tanh(Wh@Q + Uh@(r*Q)); Q = (1-z)*Q + z*h
// Stores Q_t for every t into Q_all [T][256][32].
// ---------------------------------------------------------------------------
__global__ __launch_bounds__(256) void gru_kernel(
    const float* __restrict__ Q0,
    const float* __restrict__ Wp,     // packed 4 x 65536
    float* __restrict__ Q_all)
{
    const int j = blockIdx.x;   // column 0..31
    const int i = threadIdx.x;  // row 0..255
    __shared__ float q[RR];
    __shared__ float rq[RR];
    const float* __restrict__ Wzu = Wp;
    const float* __restrict__ Wru = Wp + 65536;
    const float* __restrict__ Whp = Wp + 2 * 65536;
    const float* __restrict__ Uhp = Wp + 3 * 65536;

    q[i] = Q0[i * CC + j];
    __syncthreads();

    for (int t = 0; t < T_STEPS; ++t) {
        float az = 0.f, ar = 0.f;
        #pragma unroll 8
        for (int kq = 0; kq < 64; ++kq) {
            float4 qv = *(const float4*)&q[kq * 4];
            float4 wz = *(const float4*)&Wzu[kq * 1024 + i * 4];
            float4 wr = *(const float4*)&Wru[kq * 1024 + i * 4];
            az += wz.x * qv.x + wz.y * qv.y + wz.z * qv.z + wz.w * qv.w;
            ar += wr.x * qv.x + wr.y * qv.y + wr.z * qv.z + wr.w * qv.w;
        }
        const float r  = sigmoidf_(ar);
        const float qi = q[i];
        rq[i] = r * qi;
        __syncthreads();

        float ah = 0.f;
        #pragma unroll 8
        for (int kq = 0; kq < 64; ++kq) {
            float4 qv = *(const float4*)&q[kq * 4];
            float4 rv = *(const float4*)&rq[kq * 4];
            float4 wh = *(const float4*)&Whp[kq * 1024 + i * 4];
            float4 uh = *(const float4*)&Uhp[kq * 1024 + i * 4];
            ah += wh.x * qv.x + wh.y * qv.y + wh.z * qv.z + wh.w * qv.w;
            ah += uh.x * rv.x + uh.y * rv.y + uh.z * rv.z + uh.w * rv.w;
        }
        const float h  = tanh_fast(ah);
        const float z  = sigmoidf_(az);
        const float qn = (1.f - z) * qi + z * h;
        __syncthreads();
        q[i] = qn;
        Q_all[t * (RR * CC) + i * CC + j] = qn;
        __syncthreads();
    }
}

// ---------------------------------------------------------------------------
// GEMM with N'=32: C[t] = (relu?)(A[t] @ B[t]),  A: M x K row-major (lda),
// B: K x 32, C: M x 32. Block: 256 threads, 128-row tile, MK=64 K-chunk.
// Thread tile: 4 rows (stride 32) x 4 cols. LDS A stride 68 floats:
// 16B-aligned (272B) and 8 rows/wave hit disjoint bank quads -> conflict-free.
// ---------------------------------------------------------------------------
template <bool RELU>
__global__ __launch_bounds__(256) void gemm_n32(
    const float* __restrict__ A, long long strideA_t, int lda, int K,
    const float* __restrict__ B, long long strideB_t,
    float* __restrict__ C, long long strideC_t)
{
    const int t    = blockIdx.y;
    const int tile = blockIdx.x;
    const int tid  = threadIdx.x;
    A += (long long)t * strideA_t + (long long)tile * 128 * lda;
    B += (long long)t * strideB_t;
    C += (long long)t * strideC_t + (long long)tile * 128 * CC;

    __shared__ float As[128 * 68];
    __shared__ float Bs[64 * 32];

    const int jg = tid & 7;    // col group: cols jg*4..jg*4+3
    const int rg = tid >> 3;   // row group 0..31: rows s*32+rg

    float4 acc[4];
    acc[0] = make_float4(0.f, 0.f, 0.f, 0.f);
    acc[1] = acc[0]; acc[2] = acc[0]; acc[3] = acc[0];

    for (int kk = 0; kk < K; kk += 64) {
        // stage A tile: 128 rows x 64 cols, float4 coalesced
        #pragma unroll
        for (int w = 0; w < 8; ++w) {
            int f   = tid + w * 256;   // float4 index 0..2047
            int row = f >> 4;
            int c4  = f & 15;
            float4 v = *(const float4*)&A[row * lda + kk + c4 * 4];
            *(float4*)&As[row * 68 + c4 * 4] = v;
        }
        // stage B tile: 64 rows x 32 cols
        #pragma unroll
        for (int w = 0; w < 2; ++w) {
            int f   = tid + w * 256;   // float4 index 0..511
            int row = f >> 3;
            int c4  = f & 7;
            float4 v = *(const float4*)&B[(kk + row) * CC + c4 * 4];
            *(float4*)&Bs[row * CC + c4 * 4] = v;
        }
        __syncthreads();

        #pragma unroll
        for (int m4 = 0; m4 < 16; ++m4) {
            float4 b0 = *(const float4*)&Bs[(m4 * 4 + 0) * CC + jg * 4];
            float4 b1 = *(const float4*)&Bs[(m4 * 4 + 1) * CC + jg * 4];
            float4 b2 = *(const float4*)&Bs[(m4 * 4 + 2) * CC + jg * 4];
            float4 b3 = *(const float4*)&Bs[(m4 * 4 + 3) * CC + jg * 4];
            #pragma unroll
            for (int s = 0; s < 4; ++s) {
                float4 a = *(const float4*)&As[(s * 32 + rg) * 68 + m4 * 4];
                acc[s].x += a.x * b0.x + a.y * b1.x + a.z * b2.x + a.w * b3.x;
                acc[s].y += a.x * b0.y + a.y * b1.y + a.z * b2.y + a.w * b3.y;
                acc[s].z += a.x * b0.z + a.y * b1.z + a.z * b2.z + a.w * b3.z;
                acc[s].w += a.x * b0.w + a.y * b1.w + a.z * b2.w + a.w * b3.w;
            }
        }
        __syncthreads();
    }

    #pragma unroll
    for (int s = 0; s < 4; ++s) {
        float4 v = acc[s];
        if (RELU) {
            v.x = fmaxf(v.x, 0.f); v.y = fmaxf(v.y, 0.f);
            v.z = fmaxf(v.z, 0.f); v.w = fmaxf(v.w, 0.f);
        }
        *(float4*)&C[(s * 32 + rg) * CC + jg * 4] = v;
    }
}

// ---------------------------------------------------------------------------
extern "C" void kernel_launch(void* const* d_in, const int* in_sizes, int n_in,
                              void* d_out, int out_size, void* d_ws, size_t ws_size,
                              hipStream_t stream)
{
    const float* A  = (const float*)d_in[0];  // [1,T,N,N]
    const float* X  = (const float*)d_in[1];  // [T,N,R]
    const float* Q0 = (const float*)d_in[2];  // [R,C]
    const float* Wz = (const float*)d_in[3];
    const float* Uz = (const float*)d_in[4];
    const float* Wr = (const float*)d_in[5];
    const float* Ur = (const float*)d_in[6];
    const float* Wh = (const float*)d_in[7];
    const float* Uh = (const float*)d_in[8];
    float* out = (float*)d_out;               // [T,N,C]

    float* wp   = (float*)d_ws;               // 4*65536 floats = 1 MB
    float* qall = wp + 4 * 65536;             // 16*8192 floats  = 512 KB
    float* y    = qall + T_STEPS * RR * CC;   // 16*4096*32      = 8 MB

    pack_w<<<dim3(256, 4), 256, 0, stream>>>(Wz, Uz, Wr, Ur, Wh, Uh, wp);
    gru_kernel<<<dim3(32), 256, 0, stream>>>(Q0, wp, qall);
    // Y[t] = X[t] @ Q[t]
    gemm_n32<false><<<dim3(NN / 128, T_STEPS), 256, 0, stream>>>(
        X, (long long)NN * RR, RR, RR, qall, (long long)RR * CC,
        y, (long long)NN * CC);
    // out[t] = relu(A[t] @ Y[t])
    gemm_n32<true><<<dim3(NN / 128, T_STEPS), 256, 0, stream>>>(
        A, (long long)NN * NN, NN, NN, y, (long long)NN * CC,
        out, (long long)NN * CC);
}